// Round 18
// baseline (3219.813 us; speedup 1.0000x reference)
//
#include <hip/hip_runtime.h>
#include <cstdio>
#include <cstdint>

#define TT    20
#define BATCH 512
#define HID   1024
#define G4    4096
#define NG    8192          // both directions' gates, merged per stream
#define BT    (BATCH * TT)  // 10240
#define NCLS  200
#define SH    ((size_t)BATCH * HID)

typedef unsigned short u16;
typedef __attribute__((ext_vector_type(8))) short short8;   // 8 bf16 (4 VGPRs)
typedef __attribute__((ext_vector_type(4))) float f32x4;
typedef __attribute__((ext_vector_type(4))) unsigned short u16x4;  // 8B pack

__device__ __forceinline__ float sigf(float x) { return 1.0f / (1.0f + __expf(-x)); }

__device__ __forceinline__ u16 f2bf(float x) {
    unsigned u = __float_as_uint(x);
    u += 0x7FFFu + ((u >> 16) & 1u);           // RNE
    return (u16)(u >> 16);
}
__device__ __forceinline__ float bf2f(u16 b) { return __uint_as_float(((unsigned)b) << 16); }

// async 16B global -> LDS; LDS dest must be linear in lane order
__device__ __forceinline__ void gld16(const u16* g, u16* l) {
    __builtin_amdgcn_global_load_lds(
        (const __attribute__((address_space(1))) void*)g,
        (__attribute__((address_space(3))) void*)l, 16, 0, 0);
}

// vectorized fp32 -> plain bf16 convert
__global__ void cvt4_kernel(const float* __restrict__ x, u16* __restrict__ y, int n4)
{
    const int stride = gridDim.x * blockDim.x;
    for (int i = blockIdx.x * blockDim.x + threadIdx.x; i < n4; i += stride) {
        const float4 v = ((const float4*)x)[i];
        uint2 hp;
        hp.x = (unsigned)f2bf(v.x) | ((unsigned)f2bf(v.y) << 16);
        hp.y = (unsigned)f2bf(v.z) | ((unsigned)f2bf(v.w) << 16);
        ((uint2*)y)[i] = hp;
    }
}

// batched cvt: blockIdx.y selects job (all jobs same n4)
struct CvtJob { const float* src; u16* dst; };
struct CvtBatch { CvtJob j[6]; };
__global__ void cvt4_batch(CvtBatch cb, int n4)
{
    const float* __restrict__ x = cb.j[blockIdx.y].src;
    u16* __restrict__ y = cb.j[blockIdx.y].dst;
    const int stride = gridDim.x * blockDim.x;
    for (int i = blockIdx.x * blockDim.x + threadIdx.x; i < n4; i += stride) {
        const float4 v = ((const float4*)x)[i];
        uint2 hp;
        hp.x = (unsigned)f2bf(v.x) | ((unsigned)f2bf(v.y) << 16);
        hp.y = (unsigned)f2bf(v.z) | ((unsigned)f2bf(v.w) << 16);
        ((uint2*)y)[i] = hp;
    }
}

// audio features: (b*20+t) rows -> bf16 rows at (t*512+b)  [t-major for G consumer]
__global__ void cvtperm_audio(const float* __restrict__ in, u16* __restrict__ out)
{
    const int tid4 = blockIdx.x * blockDim.x + threadIdx.x;   // 4 elems each
    if (tid4 >= BT * 128 / 4) return;
    const int row = tid4 >> 5;           // / (128/4)
    const int kk  = (tid4 & 31) << 2;
    const int t = row % 20, b = row / 20;
    const float4 v = *(const float4*)(in + (size_t)row * 128 + kk);
    uint2 hp;
    hp.x = (unsigned)f2bf(v.x) | ((unsigned)f2bf(v.y) << 16);
    hp.y = (unsigned)f2bf(v.z) | ((unsigned)f2bf(v.w) << 16);
    *(uint2*)(out + (size_t)(t * 512 + b) * 128 + kk) = hp;
}

// W_audio (1024x128) -> bf16 transpose (128x1024)
__global__ void transpose_cvt(const float* __restrict__ in, u16* __restrict__ out)
{
    const int idx = blockIdx.x * blockDim.x + threadIdx.x;
    if (idx >= 128 * 1024) return;
    const int a = idx >> 10, p = idx & 1023;
    out[idx] = f2bf(in[p * 128 + a]);
}

// bvec[n] = dot(Wih_dir(n) row, b_audio) + bih+bhh   (fp32, wave-per-row)
__global__ void bvec_kernel(const float* __restrict__ Wih0, const float* __restrict__ Wih1,
                            const float* __restrict__ ba,
                            const float* __restrict__ bi0, const float* __restrict__ bh0,
                            const float* __restrict__ bi1, const float* __restrict__ bh1,
                            float* __restrict__ bvec)
{
    const int wv = blockIdx.x * 4 + (threadIdx.x >> 6);   // 0..8191
    const int lane = threadIdx.x & 63;
    const float* Wrow = (wv < 4096) ? Wih0 + (size_t)wv * 1024
                                    : Wih1 + (size_t)(wv - 4096) * 1024;
    float s = 0.f;
#pragma unroll
    for (int c = 0; c < 4; ++c) {
        const float4 w = *(const float4*)(Wrow + c * 256 + lane * 4);
        const float4 x = *(const float4*)(ba + c * 256 + lane * 4);
        s += w.x * x.x + w.y * x.y + w.z * x.z + w.w * x.w;
    }
#pragma unroll
    for (int o = 32; o; o >>= 1) s += __shfl_xor(s, o);
    if (lane == 0) {
        const int n = wv & 4095;
        bvec[wv] = s + ((wv < 4096) ? bi0[n] + bh0[n] : bi1[n] + bh1[n]);
    }
}

// bcat[0:4096] = bih0+bhh0 ; bcat[4096:8192] = bih1+bhh1
__global__ void bias_cat_kernel(const float* __restrict__ bi0, const float* __restrict__ bh0,
                                const float* __restrict__ bi1, const float* __restrict__ bh1,
                                float* __restrict__ bcat)
{
    const int n = blockIdx.x * blockDim.x + threadIdx.x;
    if (n >= NG) return;
    bcat[n] = (n < G4) ? (bi0[n] + bh0[n]) : (bi1[n - G4] + bh1[n - G4]);
}

// ---------------------------------------------------------------------------
// Pure-bf16 MFMA GEMM, DOUBLE-BUFFERED K-loop (1 barrier/iter, step-kernel
// proven pattern): C = A[M,K] @ W[N,K]^T + b.
// AFP32: A is fp32, reg-staged + f2bf on the fly (fused cvt; W via gld16).
// MODE 0 (proj): [M][N] bf16 out, rows PERMUTED b-major -> t-major.
// MODE 1 (G): PACK4 out [M/4][N][4] bf16, 8B NT stores (full-line segs).
// MODE 2: plain [M][N] bf16 out.
// 128x128, BK=32, 4 waves. LDS 32KB (2 buf x (8KB A + 8KB W)).
// 1D grid, bijective XCD swizzle + chunked supertile (cm=8: per-XCD A ~2MB).
// ---------------------------------------------------------------------------
template<int MODE, bool AFP32>
__launch_bounds__(256)
__global__ void gemm_b16(const u16* __restrict__ A, const float* __restrict__ Af,
                         const u16* __restrict__ W,
                         const float* __restrict__ b1, u16* __restrict__ Cb,
                         int M, int N, int K, int cm)
{
    __shared__ u16 sA[2][4][128][8];   // 2 x 8 KB
    __shared__ u16 sW[2][4][128][8];   // 2 x 8 KB
    const int tid = threadIdx.x, lane = tid & 63, w = tid >> 6;
    const int wr = w >> 1, wc = w & 1;

    const int nwg = gridDim.x;
    const int cpx = nwg >> 3;
    const int lg = (blockIdx.x & 7) * cpx + (blockIdx.x >> 3);
    const int nby = N >> 7;
    const int cb = cm * nby;
    const int chunk = lg / cb;
    const int r = lg - chunk * cb;
    const int m0 = (chunk * cm + (r % cm)) * 128;
    const int n0 = (r / cm) * 128;

    const u16*   A0  = AFP32 ? nullptr : A + (size_t)m0 * K;
    const float* A0f = AFP32 ? Af + (size_t)m0 * K : nullptr;
    const u16*   W0  = W + (size_t)n0 * K;

    f32x4 acc[4][4];
#pragma unroll
    for (int i = 0; i < 4; ++i)
#pragma unroll
        for (int j = 0; j < 4; ++j) acc[i][j] = f32x4{0.f, 0.f, 0.f, 0.f};

    const int u1 = tid, u2 = tid + 256;
    const size_t go1 = (size_t)(u1 & 127) * K + (u1 >> 7) * 8;
    const size_t go2 = (size_t)(u2 & 127) * K + (u2 >> 7) * 8;
    u16* const ldA1 = (u16*)sA + (size_t)u1 * 8;   // + buf*4096 elems
    u16* const ldA2 = (u16*)sA + (size_t)u2 * 8;
    u16* const ldW1 = (u16*)sW + (size_t)u1 * 8;
    u16* const ldW2 = (u16*)sW + (size_t)u2 * 8;

    // stage(k, buf): A (fp32->bf16 reg-staged, or gld16) + W gld16
    auto stageA = [&](int kk, int buf) {
        if (AFP32) {
            const float4 x0 = *(const float4*)(A0f + go1 + kk);
            const float4 x1 = *(const float4*)(A0f + go1 + kk + 4);
            const float4 y0 = *(const float4*)(A0f + go2 + kk);
            const float4 y1 = *(const float4*)(A0f + go2 + kk + 4);
            u16 hb[8];
            hb[0] = f2bf(x0.x); hb[1] = f2bf(x0.y); hb[2] = f2bf(x0.z); hb[3] = f2bf(x0.w);
            hb[4] = f2bf(x1.x); hb[5] = f2bf(x1.y); hb[6] = f2bf(x1.z); hb[7] = f2bf(x1.w);
            *(uint4*)(ldA1 + buf * 4096) = *(uint4*)hb;
            hb[0] = f2bf(y0.x); hb[1] = f2bf(y0.y); hb[2] = f2bf(y0.z); hb[3] = f2bf(y0.w);
            hb[4] = f2bf(y1.x); hb[5] = f2bf(y1.y); hb[6] = f2bf(y1.z); hb[7] = f2bf(y1.w);
            *(uint4*)(ldA2 + buf * 4096) = *(uint4*)hb;
        } else {
            gld16(A0 + go1 + kk, ldA1 + buf * 4096);
            gld16(A0 + go2 + kk, ldA2 + buf * 4096);
        }
    };

    // prologue
    stageA(0, 0);
    gld16(W0 + go1, ldW1);
    gld16(W0 + go2, ldW2);
    __syncthreads();

    for (int k0 = 0; k0 < K; k0 += 32) {
        const int bf = (k0 >> 5) & 1;
        if (k0 + 32 < K) {
            stageA(k0 + 32, bf ^ 1);
            gld16(W0 + go1 + k0 + 32, ldW1 + (bf ^ 1) * 4096);
            gld16(W0 + go2 + k0 + 32, ldW2 + (bf ^ 1) * 4096);
        }
        const int kb = lane >> 4, rr = lane & 15;
        short8 Av[4], Wv[4];
#pragma unroll
        for (int i = 0; i < 4; ++i) {
            Av[i] = *(const short8*)&sA[bf][kb][wr * 64 + i * 16 + rr][0];
            Wv[i] = *(const short8*)&sW[bf][kb][wc * 64 + i * 16 + rr][0];
        }
#pragma unroll
        for (int i = 0; i < 4; ++i)
#pragma unroll
            for (int j = 0; j < 4; ++j)
                acc[i][j] = __builtin_amdgcn_mfma_f32_16x16x32_bf16(Av[i], Wv[j], acc[i][j], 0, 0, 0);
        __syncthreads();
    }

    const int rr = lane & 15, rg = lane >> 4;
#pragma unroll
    for (int j = 0; j < 4; ++j) {
        const int col = n0 + wc * 64 + j * 16 + rr;
        const float bias = b1 ? b1[col] : 0.f;
#pragma unroll
        for (int i = 0; i < 4; ++i) {
            if (MODE == 1) {
                u16x4 pk;
#pragma unroll
                for (int q = 0; q < 4; ++q) pk[q] = f2bf(acc[i][j][q] + bias);
                const int grp = (m0 >> 2) + wr * 16 + i * 4 + rg;
                __builtin_nontemporal_store(pk, (u16x4*)(Cb + ((size_t)grp * N + col) * 4));
            } else if (MODE == 0) {
#pragma unroll
                for (int q = 0; q < 4; ++q) {
                    const int row = m0 + wr * 64 + i * 16 + rg * 4 + q;
                    const int rowp = (row % 20) * 512 + row / 20;   // b-major -> t-major
                    Cb[(size_t)rowp * N + col] = f2bf(acc[i][j][q] + bias);
                }
            } else {
#pragma unroll
                for (int q = 0; q < 4; ++q) {
                    const int row = m0 + wr * 64 + i * 16 + rg * 4 + q;
                    Cb[(size_t)row * N + col] = f2bf(acc[i][j][q] + bias);
                }
            }
        }
    }
}

// ---------------------------------------------------------------------------
// Merged 6-LSTM step (R14-proven shape): gates = h_in @ Whh^T + G, cell update.
// Block: 256 threads = 4 waves, tile 64 batch x (32 j x 4 gates). 24KB LDS,
// 1536 blocks (~6/CU) — TLP hides the 2-phase barrier stall.
// G is t-major PACK4: [3][TT][BATCH/4][NG][4] bf16, 8B NT loads.
// grid (HID/32, BATCH/64, 6): j fastest -> W-tile consumers share an XCD.
// ---------------------------------------------------------------------------
__launch_bounds__(256)
__global__ void lstm_step6(const u16* __restrict__ whhAll,   // [6][4096][1024] bf16
                           const u16* __restrict__ Gall,     // pack4 t-major
                           const u16* __restrict__ hinAll,   // [6][512][1024] bf16
                           u16* __restrict__ houtAll,
                           float* __restrict__ cbAll,        // [6][512][1024] f32
                           float* __restrict__ hfinAll,      // [6][512][1024] f32
                           int s, int write_hfin)
{
    const int l = blockIdx.z;
    __shared__ u16 sA[2][4][64][8];    // 2 x 4 KB
    __shared__ u16 sW[2][4][128][8];   // 2 x 8 KB
    const int tid = threadIdx.x, lane = tid & 63, w = tid >> 6;
    const int wr = w >> 1, wc = w & 1;
    const int j0 = blockIdx.x * 32;
    const int m0 = blockIdx.y * 64;

    const u16* __restrict__ hin = hinAll + (size_t)l * SH;
    const u16* __restrict__ Whh = whhAll + (size_t)l * G4 * HID;
    const int do_gemm = (s > 0);

    f32x4 acc[2][4];
#pragma unroll
    for (int i = 0; i < 2; ++i)
#pragma unroll
        for (int g = 0; g < 4; ++g) acc[i][g] = f32x4{0.f, 0.f, 0.f, 0.f};

    const int rr = lane & 15, rg = lane >> 4;

    if (do_gemm) {
        // A: 64 rows x 32 k; thread covers row tid&63, chunk tid>>6
        const size_t goA = (size_t)(m0 + (tid & 63)) * HID + (tid >> 6) * 8;
        // W: 128 gate-interleaved rows x 32 k; two gld16 per thread
        const int rW = tid & 127;
        const int wrow = ((rW >> 4) & 3) * HID + j0 + (rW >> 6) * 16 + (rW & 15);
        const size_t goW1 = (size_t)wrow * HID + (tid >> 7) * 8;        // chunks 0-1
        const size_t goW2 = (size_t)wrow * HID + ((tid >> 7) + 2) * 8;  // chunks 2-3
        u16* const ldA  = (u16*)sA + (size_t)tid * 8;
        u16* const ldW1 = (u16*)sW + (size_t)tid * 8;
        u16* const ldW2 = (u16*)sW + (size_t)(tid + 256) * 8;

        gld16(hin + goA,  ldA);
        gld16(Whh + goW1, ldW1);
        gld16(Whh + goW2, ldW2);
        __syncthreads();

        for (int k0 = 0; k0 < HID; k0 += 32) {
            const int bf = (k0 >> 5) & 1;
            if (k0 + 32 < HID) {
                gld16(hin + goA  + k0 + 32, ldA  + (bf ^ 1) * 2048);
                gld16(Whh + goW1 + k0 + 32, ldW1 + (bf ^ 1) * 4096);
                gld16(Whh + goW2 + k0 + 32, ldW2 + (bf ^ 1) * 4096);
            }
            const int kb = lane >> 4;
            short8 Av[2], Wv[4];
#pragma unroll
            for (int i = 0; i < 2; ++i)
                Av[i] = *(const short8*)&sA[bf][kb][wr * 32 + i * 16 + rr][0];
#pragma unroll
            for (int g = 0; g < 4; ++g)
                Wv[g] = *(const short8*)&sW[bf][kb][wc * 64 + g * 16 + rr][0];
#pragma unroll
            for (int i = 0; i < 2; ++i)
#pragma unroll
                for (int g = 0; g < 4; ++g)
                    acc[i][g] = __builtin_amdgcn_mfma_f32_16x16x32_bf16(Av[i], Wv[g], acc[i][g], 0, 0, 0);
            __syncthreads();
        }
    }

    const int j = j0 + wc * 16 + rr;
    const int t = (l & 1) ? (TT - 1 - s) : s;
    const u16* __restrict__ Gl = Gall + (size_t)(l >> 1) * BT * NG;   // pack4 stream base
    const int cbase = (l & 1) * G4 + j;
    float* __restrict__ cb = cbAll + (size_t)l * SH;
    float* __restrict__ hf = hfinAll + (size_t)l * SH;
    u16* __restrict__ ho = houtAll + (size_t)l * SH;
#pragma unroll
    for (int i = 0; i < 2; ++i) {
        const int grp = t * 128 + (m0 >> 2) + wr * 8 + i * 4 + rg;
        const u16* gb = Gl + (size_t)grp * NG * 4;
        const u16x4 g0 = __builtin_nontemporal_load((const u16x4*)(gb + (size_t)cbase * 4));
        const u16x4 g1 = __builtin_nontemporal_load((const u16x4*)(gb + (size_t)(cbase + 1024) * 4));
        const u16x4 g2 = __builtin_nontemporal_load((const u16x4*)(gb + (size_t)(cbase + 2048) * 4));
        const u16x4 g3 = __builtin_nontemporal_load((const u16x4*)(gb + (size_t)(cbase + 3072) * 4));
#pragma unroll
        for (int q = 0; q < 4; ++q) {
            const int b = m0 + wr * 32 + i * 16 + rg * 4 + q;
            const float pi = acc[i][0][q] + bf2f(g0[q]);
            const float pf = acc[i][1][q] + bf2f(g1[q]);
            const float pg = acc[i][2][q] + bf2f(g2[q]);
            const float po = acc[i][3][q] + bf2f(g3[q]);
            const size_t idx = (size_t)b * HID + j;
            const float cprev = do_gemm ? cb[idx] : 0.f;
            const float cn = sigf(pf) * cprev + sigf(pi) * tanhf(pg);
            cb[idx] = cn;
            const float h = sigf(po) * tanhf(cn);
            if (write_hfin) hf[idx] = h;
            else            ho[idx] = f2bf(h);
        }
    }
}

// fused[b, n] = prod over streams of concat(h_fwd, h_rev); hfin layout [l][b][j]
__global__ void fuse_mul_kernel(const float* __restrict__ hfin, float* __restrict__ fused)
{
    const int idx = blockIdx.x * blockDim.x + threadIdx.x;
    if (idx >= BATCH * 2 * HID) return;
    const int b = idx >> 11;
    const int n = idx & 2047;
    const int half = n >> 10;
    const int j = n & 1023;
    const size_t o = (size_t)b * HID + j;
    fused[idx] = hfin[(size_t)(0 + half) * SH + o] *
                 hfin[(size_t)(2 + half) * SH + o] *
                 hfin[(size_t)(4 + half) * SH + o];
}

// fp32 vector GEMM for the small classifier (N=200): C = A@W^T + b
__launch_bounds__(256)
__global__ void gemm_bias_kernel(const float* __restrict__ A, const float* __restrict__ W,
                                 const float* __restrict__ b1,
                                 float* __restrict__ C, int M, int N, int K)
{
    __shared__ float As[16][68];
    __shared__ float Ws[16][68];
    const int tid = threadIdx.x;
    const int tx = tid & 15, ty = tid >> 4;
    const int m0 = blockIdx.x * 64;
    const int n0 = blockIdx.y * 64;
    const int lr = tid >> 2;
    const int lk = (tid & 3) << 2;
    const bool mok = (m0 + lr < M);
    const bool nok = (n0 + lr < N);
    const float* Arow = A + (size_t)(m0 + lr) * K + lk;
    const float* Wrow = W + (size_t)(n0 + lr) * K + lk;
    float acc[4][4] = {};

    for (int k0 = 0; k0 < K; k0 += 16) {
        float4 av = make_float4(0.f, 0.f, 0.f, 0.f);
        float4 wv = make_float4(0.f, 0.f, 0.f, 0.f);
        if (mok) av = *(const float4*)(Arow + k0);
        if (nok) wv = *(const float4*)(Wrow + k0);
        As[lk + 0][lr] = av.x; As[lk + 1][lr] = av.y; As[lk + 2][lr] = av.z; As[lk + 3][lr] = av.w;
        Ws[lk + 0][lr] = wv.x; Ws[lk + 1][lr] = wv.y; Ws[lk + 2][lr] = wv.z; Ws[lk + 3][lr] = wv.w;
        __syncthreads();
#pragma unroll
        for (int k = 0; k < 16; ++k) {
            const float4 a = *(const float4*)&As[k][ty << 2];
            const float4 ww = *(const float4*)&Ws[k][tx << 2];
            const float a4[4] = {a.x, a.y, a.z, a.w};
            const float w4[4] = {ww.x, ww.y, ww.z, ww.w};
#pragma unroll
            for (int i = 0; i < 4; ++i)
#pragma unroll
                for (int j = 0; j < 4; ++j)
                    acc[i][j] = fmaf(a4[i], w4[j], acc[i][j]);
        }
        __syncthreads();
    }

#pragma unroll
    for (int i = 0; i < 4; ++i) {
        const int m = m0 + (ty << 2) + i;
        if (m >= M) continue;
#pragma unroll
        for (int j = 0; j < 4; ++j) {
            const int n = n0 + (tx << 2) + j;
            if (n >= N) continue;
            C[(size_t)m * N + n] = acc[i][j] + (b1 ? b1[n] : 0.f);
        }
    }
}

extern "C" void kernel_launch(void* const* d_in, const int* in_sizes, int n_in,
                              void* d_out, int out_size, void* d_ws, size_t ws_size,
                              hipStream_t stream)
{
    const float* resnet   = (const float*)d_in[0];
    const float* c3d      = (const float*)d_in[1];
    const float* audio    = (const float*)d_in[2];
    const float* W_audio  = (const float*)d_in[3];
    const float* b_audio  = (const float*)d_in[4];
    const float* W_resnet = (const float*)d_in[5];
    const float* b_resnet = (const float*)d_in[6];
    const float* W_c3d    = (const float*)d_in[7];
    const float* b_c3d    = (const float*)d_in[8];
    const float* Wih[6]; const float* Whh[6]; const float* bih[6]; const float* bhh[6];
    for (int l = 0; l < 6; ++l) {
        Wih[l] = (const float*)d_in[9 + 4 * l];
        Whh[l] = (const float*)d_in[10 + 4 * l];
        bih[l] = (const float*)d_in[11 + 4 * l];
        bhh[l] = (const float*)d_in[12 + 4 * l];
    }
    const float* W_out = (const float*)d_in[33];
    const float* b_out = (const float*)d_in[34];
    float* out = (float*)d_out;

    const float* feat[3] = { audio, resnet, c3d };
    const float* fw[3]   = { W_audio, W_resnet, W_c3d };
    const float* fb[3]   = { b_audio, b_resnet, b_c3d };
    const int    fK[3]   = { 128, 2048, 4096 };

    // ---- workspace carve (bytes) ----
    char* p = (char*)d_ws;
    char* pend = p + ws_size;
    auto alloc = [&](size_t bytes) -> void* {
        void* q = p; p += (bytes + 255) & ~(size_t)255; return q;
    };
    const size_t FW = (size_t)1024 * (128 + 2048 + 4096);
    u16* Gall  = (u16*)alloc((size_t)3 * BT * NG * 2);       // 503 MB, bf16 pack4 t-major
    u16* fwB   = (u16*)alloc(FW * 2);
    u16* wihB  = (u16*)alloc((size_t)NG * HID * 2);          // reused per stream
    u16* whhB  = (u16*)alloc((size_t)3 * NG * HID * 2);      // all 6, [l][4096][1024]
    u16* projB = (u16*)alloc((size_t)BT * HID * 2);          // t-major rows
    float* bcat = (float*)alloc((size_t)NG * 4);
    u16* hA    = (u16*)alloc((size_t)6 * SH * 2);
    u16* hB    = (u16*)alloc((size_t)6 * SH * 2);
    float* cb    = (float*)alloc((size_t)6 * SH * 4);
    float* hfin  = (float*)alloc((size_t)6 * SH * 4);
    float* fused = (float*)alloc((size_t)BATCH * 2 * HID * 4);
    // audio fast-path buffers
    u16* waT      = (u16*)alloc((size_t)128 * 1024 * 2);     // W_audio^T bf16
    u16* wcombB   = (u16*)alloc((size_t)NG * 128 * 2);       // Wih_audio @ W_audio, bf16
    u16* featPerm = (u16*)alloc((size_t)BT * 128 * 2);       // audio feats t-major bf16
    float* bvec   = (float*)alloc((size_t)NG * 4);
    if (p > pend) {
        fprintf(stderr, "kernel_launch: ws too small: need %zu have %zu\n",
                (size_t)(p - (char*)d_ws), ws_size);
        return;
    }

    const dim3 blk(256);
    const size_t fwOff[3] = { 0, (size_t)1024 * 128, (size_t)1024 * 128 + (size_t)1024 * 2048 };
    const int n4w = (G4 * HID) / 4;

    // cvt resnet/c3d projection weights to bf16 (audio uses the fused path)
    for (int st = 1; st < 3; ++st) {
        const int n4 = (1024 * fK[st]) / 4;
        cvt4_kernel<<<dim3(min(2048, (n4 + 255) / 256)), blk, 0, stream>>>(
            fw[st], fwB + fwOff[st], n4);
    }
    // all 6 Whh in one batched launch
    {
        CvtBatch b6;
        for (int l = 0; l < 6; ++l) { b6.j[l].src = Whh[l]; b6.j[l].dst = whhB + (size_t)l * G4 * HID; }
        cvt4_batch<<<dim3(768, 6), blk, 0, stream>>>(b6, n4w);
    }

    // ---- stream 0 (audio), fused: G_a = feat_a @ (Wih_a W_a)^T + (Wih_a b_a + bcat) ----
    {
        CvtBatch b2;
        for (int d = 0; d < 2; ++d) { b2.j[d].src = Wih[d]; b2.j[d].dst = wihB + (size_t)d * G4 * HID; }
        cvt4_batch<<<dim3(768, 2), blk, 0, stream>>>(b2, n4w);
        transpose_cvt<<<dim3(512), blk, 0, stream>>>(W_audio, waT);
        // Wcomb (8192 x 128) = wihB (8192x1024) @ waT^T
        gemm_b16<2, false><<<dim3(64), blk, 0, stream>>>(
            wihB, nullptr, waT, nullptr, wcombB, NG, 128, 1024, 8);
        bvec_kernel<<<dim3(2048), blk, 0, stream>>>(
            Wih[0], Wih[1], b_audio, bih[0], bhh[0], bih[1], bhh[1], bvec);
        cvtperm_audio<<<dim3((BT * 128 / 4 + 255) / 256), blk, 0, stream>>>(audio, featPerm);
        // G_audio (pack4 t-major) = featPerm (BTx128) @ wcombB^T + bvec, K=128
        gemm_b16<1, false><<<dim3((BT / 128) * (NG / 128)), blk, 0, stream>>>(
            featPerm, nullptr, wcombB, bvec, Gall, BT, NG, 128, 8);
    }

    // ---- streams 1,2: fused-cvt proj (fp32 A) -> Wih cvt -> G-GEMM ----
    for (int st = 1; st < 3; ++st) {
        const int K = fK[st];
        // proj (t-major bf16 out) straight from fp32 features — cvt fused into staging
        gemm_b16<0, true><<<dim3((BT / 128) * (HID / 128)), blk, 0, stream>>>(
            nullptr, feat[st], fwB + fwOff[st], fb[st], projB, BT, HID, K, 8);
        {
            CvtBatch b2;
            for (int d = 0; d < 2; ++d) {
                b2.j[d].src = Wih[st * 2 + d];
                b2.j[d].dst = wihB + (size_t)d * G4 * HID;
            }
            cvt4_batch<<<dim3(768, 2), blk, 0, stream>>>(b2, n4w);
        }
        bias_cat_kernel<<<dim3(NG / 256), blk, 0, stream>>>(
            bih[st * 2], bhh[st * 2], bih[st * 2 + 1], bhh[st * 2 + 1], bcat);
        gemm_b16<1, false><<<dim3((BT / 128) * (NG / 128)), blk, 0, stream>>>(
            projB, nullptr, wihB, bcat, Gall + (size_t)st * BT * NG, BT, NG, HID, 8);
    }

    // ---- merged recurrence: 20 launches, all 6 LSTMs per launch ----
    for (int s = 0; s < TT; ++s) {
        const u16* in = (s & 1) ? hB : hA;
        u16*      o  = (s & 1) ? hA : hB;
        lstm_step6<<<dim3(HID / 32, BATCH / 64, 6), blk, 0, stream>>>(
            whhB, Gall, in, o, cb, hfin, s, s == TT - 1 ? 1 : 0);
    }

    // fused elementwise product
    fuse_mul_kernel<<<dim3((BATCH * 2 * HID) / 256), blk, 0, stream>>>(hfin, fused);

    // classifier
    gemm_bias_kernel<<<dim3(BATCH / 64, (NCLS + 63) / 64), blk, 0, stream>>>(
        fused, W_out, b_out, out, BATCH, NCLS, 2 * HID);
}

// Round 19
// 3044.858 us; speedup vs baseline: 1.0575x; 1.0575x over previous
//
#include <hip/hip_runtime.h>
#include <cstdio>
#include <cstdint>

#define TT    20
#define BATCH 512
#define HID   1024
#define G4    4096
#define NG    8192          // both directions' gates, merged per stream
#define BT    (BATCH * TT)  // 10240
#define NCLS  200
#define SH    ((size_t)BATCH * HID)

typedef unsigned short u16;
typedef __attribute__((ext_vector_type(8))) short short8;   // 8 bf16 (4 VGPRs)
typedef __attribute__((ext_vector_type(4))) float f32x4;
typedef __attribute__((ext_vector_type(4))) unsigned short u16x4;  // 8B pack

__device__ __forceinline__ float sigf(float x) { return 1.0f / (1.0f + __expf(-x)); }

__device__ __forceinline__ u16 f2bf(float x) {
    unsigned u = __float_as_uint(x);
    u += 0x7FFFu + ((u >> 16) & 1u);           // RNE
    return (u16)(u >> 16);
}
__device__ __forceinline__ float bf2f(u16 b) { return __uint_as_float(((unsigned)b) << 16); }

// async 16B global -> LDS; LDS dest must be linear in lane order
__device__ __forceinline__ void gld16(const u16* g, u16* l) {
    __builtin_amdgcn_global_load_lds(
        (const __attribute__((address_space(1))) void*)g,
        (__attribute__((address_space(3))) void*)l, 16, 0, 0);
}

// vectorized fp32 -> plain bf16 convert
__global__ void cvt4_kernel(const float* __restrict__ x, u16* __restrict__ y, int n4)
{
    const int stride = gridDim.x * blockDim.x;
    for (int i = blockIdx.x * blockDim.x + threadIdx.x; i < n4; i += stride) {
        const float4 v = ((const float4*)x)[i];
        uint2 hp;
        hp.x = (unsigned)f2bf(v.x) | ((unsigned)f2bf(v.y) << 16);
        hp.y = (unsigned)f2bf(v.z) | ((unsigned)f2bf(v.w) << 16);
        ((uint2*)y)[i] = hp;
    }
}

// batched cvt: blockIdx.y selects job (all jobs same n4)
struct CvtJob { const float* src; u16* dst; };
struct CvtBatch { CvtJob j[6]; };
__global__ void cvt4_batch(CvtBatch cb, int n4)
{
    const float* __restrict__ x = cb.j[blockIdx.y].src;
    u16* __restrict__ y = cb.j[blockIdx.y].dst;
    const int stride = gridDim.x * blockDim.x;
    for (int i = blockIdx.x * blockDim.x + threadIdx.x; i < n4; i += stride) {
        const float4 v = ((const float4*)x)[i];
        uint2 hp;
        hp.x = (unsigned)f2bf(v.x) | ((unsigned)f2bf(v.y) << 16);
        hp.y = (unsigned)f2bf(v.z) | ((unsigned)f2bf(v.w) << 16);
        ((uint2*)y)[i] = hp;
    }
}

// audio features: (b*20+t) rows -> bf16 rows at (t*512+b)  [t-major for G consumer]
__global__ void cvtperm_audio(const float* __restrict__ in, u16* __restrict__ out)
{
    const int tid4 = blockIdx.x * blockDim.x + threadIdx.x;   // 4 elems each
    if (tid4 >= BT * 128 / 4) return;
    const int row = tid4 >> 5;           // / (128/4)
    const int kk  = (tid4 & 31) << 2;
    const int t = row % 20, b = row / 20;
    const float4 v = *(const float4*)(in + (size_t)row * 128 + kk);
    uint2 hp;
    hp.x = (unsigned)f2bf(v.x) | ((unsigned)f2bf(v.y) << 16);
    hp.y = (unsigned)f2bf(v.z) | ((unsigned)f2bf(v.w) << 16);
    *(uint2*)(out + (size_t)(t * 512 + b) * 128 + kk) = hp;
}

// W_audio (1024x128) -> bf16 transpose (128x1024)
__global__ void transpose_cvt(const float* __restrict__ in, u16* __restrict__ out)
{
    const int idx = blockIdx.x * blockDim.x + threadIdx.x;
    if (idx >= 128 * 1024) return;
    const int a = idx >> 10, p = idx & 1023;
    out[idx] = f2bf(in[p * 128 + a]);
}

// bvec[n] = dot(Wih_dir(n) row, b_audio) + bih+bhh   (fp32, wave-per-row)
__global__ void bvec_kernel(const float* __restrict__ Wih0, const float* __restrict__ Wih1,
                            const float* __restrict__ ba,
                            const float* __restrict__ bi0, const float* __restrict__ bh0,
                            const float* __restrict__ bi1, const float* __restrict__ bh1,
                            float* __restrict__ bvec)
{
    const int wv = blockIdx.x * 4 + (threadIdx.x >> 6);   // 0..8191
    const int lane = threadIdx.x & 63;
    const float* Wrow = (wv < 4096) ? Wih0 + (size_t)wv * 1024
                                    : Wih1 + (size_t)(wv - 4096) * 1024;
    float s = 0.f;
#pragma unroll
    for (int c = 0; c < 4; ++c) {
        const float4 w = *(const float4*)(Wrow + c * 256 + lane * 4);
        const float4 x = *(const float4*)(ba + c * 256 + lane * 4);
        s += w.x * x.x + w.y * x.y + w.z * x.z + w.w * x.w;
    }
#pragma unroll
    for (int o = 32; o; o >>= 1) s += __shfl_xor(s, o);
    if (lane == 0) {
        const int n = wv & 4095;
        bvec[wv] = s + ((wv < 4096) ? bi0[n] + bh0[n] : bi1[n] + bh1[n]);
    }
}

// bcat[0:4096] = bih0+bhh0 ; bcat[4096:8192] = bih1+bhh1
__global__ void bias_cat_kernel(const float* __restrict__ bi0, const float* __restrict__ bh0,
                                const float* __restrict__ bi1, const float* __restrict__ bh1,
                                float* __restrict__ bcat)
{
    const int n = blockIdx.x * blockDim.x + threadIdx.x;
    if (n >= NG) return;
    bcat[n] = (n < G4) ? (bi0[n] + bh0[n]) : (bi1[n - G4] + bh1[n - G4]);
}

// ---------------------------------------------------------------------------
// Pure-bf16 MFMA GEMM (m97 structure, single-buffer — dbuf proven neutral):
// C = A[M,K]bf16 @ W[N,K]bf16^T + b.
// MODE 0 (proj): [M][N] bf16 output, rows PERMUTED b-major -> t-major.
// MODE 1 (G): PACK4 output [M/4][N][4] bf16, 8B NT stores (full-line segs).
// MODE 2: plain [M][N] bf16 output (Wcomb path).
// 128x128, BK=32, 4 waves, global_load_lds staging, 16 MFMA/iter.
// 1D grid, bijective XCD swizzle + chunked supertile (cm=8: per-XCD A ~2MB).
// ---------------------------------------------------------------------------
template<int MODE>
__launch_bounds__(256)
__global__ void gemm_b16(const u16* __restrict__ A, const u16* __restrict__ W,
                         const float* __restrict__ b1, u16* __restrict__ Cb,
                         int M, int N, int K, int cm)
{
    __shared__ u16 sA[4][128][8]; __shared__ u16 sW[4][128][8];
    const int tid = threadIdx.x, lane = tid & 63, w = tid >> 6;
    const int wr = w >> 1, wc = w & 1;

    const int nwg = gridDim.x;
    const int cpx = nwg >> 3;
    const int lg = (blockIdx.x & 7) * cpx + (blockIdx.x >> 3);
    const int nby = N >> 7;
    const int cb = cm * nby;
    const int chunk = lg / cb;
    const int r = lg - chunk * cb;
    const int m0 = (chunk * cm + (r % cm)) * 128;
    const int n0 = (r / cm) * 128;

    const u16* A0 = A + (size_t)m0 * K;
    const u16* W0 = W + (size_t)n0 * K;

    f32x4 acc[4][4];
#pragma unroll
    for (int i = 0; i < 4; ++i)
#pragma unroll
        for (int j = 0; j < 4; ++j) acc[i][j] = f32x4{0.f, 0.f, 0.f, 0.f};

    const int u1 = tid, u2 = tid + 256;
    const size_t go1 = (size_t)(u1 & 127) * K + (u1 >> 7) * 8;
    const size_t go2 = (size_t)(u2 & 127) * K + (u2 >> 7) * 8;
    u16* const l1 = (u16*)sA + (size_t)u1 * 8;
    u16* const l2 = (u16*)sA + (size_t)u2 * 8;
    const size_t dW = (u16*)sW - (u16*)sA;

    for (int k0 = 0; k0 < K; k0 += 32) {
        gld16(A0 + go1 + k0, l1);       gld16(A0 + go2 + k0, l2);
        gld16(W0 + go1 + k0, l1 + dW);  gld16(W0 + go2 + k0, l2 + dW);
        __syncthreads();

        const int kb = lane >> 4, rr = lane & 15;
        short8 Av[4], Wv[4];
#pragma unroll
        for (int i = 0; i < 4; ++i) {
            Av[i] = *(const short8*)&sA[kb][wr * 64 + i * 16 + rr][0];
            Wv[i] = *(const short8*)&sW[kb][wc * 64 + i * 16 + rr][0];
        }
#pragma unroll
        for (int i = 0; i < 4; ++i)
#pragma unroll
            for (int j = 0; j < 4; ++j)
                acc[i][j] = __builtin_amdgcn_mfma_f32_16x16x32_bf16(Av[i], Wv[j], acc[i][j], 0, 0, 0);
        __syncthreads();
    }

    const int rr = lane & 15, rg = lane >> 4;
#pragma unroll
    for (int j = 0; j < 4; ++j) {
        const int col = n0 + wc * 64 + j * 16 + rr;
        const float bias = b1 ? b1[col] : 0.f;
#pragma unroll
        for (int i = 0; i < 4; ++i) {
            if (MODE == 1) {
                u16x4 pk;
#pragma unroll
                for (int q = 0; q < 4; ++q) pk[q] = f2bf(acc[i][j][q] + bias);
                const int grp = (m0 >> 2) + wr * 16 + i * 4 + rg;
                __builtin_nontemporal_store(pk, (u16x4*)(Cb + ((size_t)grp * N + col) * 4));
            } else if (MODE == 0) {
#pragma unroll
                for (int q = 0; q < 4; ++q) {
                    const int row = m0 + wr * 64 + i * 16 + rg * 4 + q;
                    const int rowp = (row % 20) * 512 + row / 20;   // b-major -> t-major
                    Cb[(size_t)rowp * N + col] = f2bf(acc[i][j][q] + bias);
                }
            } else {
#pragma unroll
                for (int q = 0; q < 4; ++q) {
                    const int row = m0 + wr * 64 + i * 16 + rg * 4 + q;
                    Cb[(size_t)row * N + col] = f2bf(acc[i][j][q] + bias);
                }
            }
        }
    }
}

// ---------------------------------------------------------------------------
// Merged 6-LSTM step (R14-proven shape + T14 G-prefetch): gates = h_in @
// Whh^T + G, cell update. G NT-loads issued at KERNEL ENTRY so their HBM
// latency hides under the K-loop (compiler can't hoist across barriers).
// Block: 256 threads = 4 waves, tile 64 batch x (32 j x 4 gates). 24KB LDS,
// 1536 blocks (~6/CU). grid (HID/32, BATCH/64, 6): j fastest -> W L2-shared.
// ---------------------------------------------------------------------------
__launch_bounds__(256)
__global__ void lstm_step6(const u16* __restrict__ whhAll,   // [6][4096][1024] bf16
                           const u16* __restrict__ Gall,     // pack4 t-major
                           const u16* __restrict__ hinAll,   // [6][512][1024] bf16
                           u16* __restrict__ houtAll,
                           float* __restrict__ cbAll,        // [6][512][1024] f32
                           float* __restrict__ hfinAll,      // [6][512][1024] f32
                           int s, int write_hfin)
{
    const int l = blockIdx.z;
    __shared__ u16 sA[2][4][64][8];    // 2 x 4 KB
    __shared__ u16 sW[2][4][128][8];   // 2 x 8 KB
    const int tid = threadIdx.x, lane = tid & 63, w = tid >> 6;
    const int wr = w >> 1, wc = w & 1;
    const int j0 = blockIdx.x * 32;
    const int m0 = blockIdx.y * 64;

    const u16* __restrict__ hin = hinAll + (size_t)l * SH;
    const u16* __restrict__ Whh = whhAll + (size_t)l * G4 * HID;
    const int do_gemm = (s > 0);

    const int rr = lane & 15, rg = lane >> 4;
    const int j = j0 + wc * 16 + rr;
    const int t = (l & 1) ? (TT - 1 - s) : s;

    // ---- T14: issue G loads up front; consumed only in the epilogue ----
    const u16* __restrict__ Gl = Gall + (size_t)(l >> 1) * BT * NG;
    const int cbase = (l & 1) * G4 + j;
    u16x4 gr[2][4];
#pragma unroll
    for (int i = 0; i < 2; ++i) {
        const int grp = t * 128 + (m0 >> 2) + wr * 8 + i * 4 + rg;
        const u16* gb = Gl + (size_t)grp * NG * 4;
        gr[i][0] = __builtin_nontemporal_load((const u16x4*)(gb + (size_t)cbase * 4));
        gr[i][1] = __builtin_nontemporal_load((const u16x4*)(gb + (size_t)(cbase + 1024) * 4));
        gr[i][2] = __builtin_nontemporal_load((const u16x4*)(gb + (size_t)(cbase + 2048) * 4));
        gr[i][3] = __builtin_nontemporal_load((const u16x4*)(gb + (size_t)(cbase + 3072) * 4));
    }

    f32x4 acc[2][4];
#pragma unroll
    for (int i = 0; i < 2; ++i)
#pragma unroll
        for (int g = 0; g < 4; ++g) acc[i][g] = f32x4{0.f, 0.f, 0.f, 0.f};

    if (do_gemm) {
        // A: 64 rows x 32 k; thread covers row tid&63, chunk tid>>6
        const size_t goA = (size_t)(m0 + (tid & 63)) * HID + (tid >> 6) * 8;
        // W: 128 gate-interleaved rows x 32 k; two gld16 per thread
        const int rW = tid & 127;
        const int wrow = ((rW >> 4) & 3) * HID + j0 + (rW >> 6) * 16 + (rW & 15);
        const size_t goW1 = (size_t)wrow * HID + (tid >> 7) * 8;        // chunks 0-1
        const size_t goW2 = (size_t)wrow * HID + ((tid >> 7) + 2) * 8;  // chunks 2-3
        u16* const ldA  = (u16*)sA + (size_t)tid * 8;
        u16* const ldW1 = (u16*)sW + (size_t)tid * 8;
        u16* const ldW2 = (u16*)sW + (size_t)(tid + 256) * 8;

        gld16(hin + goA,  ldA);
        gld16(Whh + goW1, ldW1);
        gld16(Whh + goW2, ldW2);
        __syncthreads();

        for (int k0 = 0; k0 < HID; k0 += 32) {
            const int bf = (k0 >> 5) & 1;
            if (k0 + 32 < HID) {
                gld16(hin + goA  + k0 + 32, ldA  + (bf ^ 1) * 2048);
                gld16(Whh + goW1 + k0 + 32, ldW1 + (bf ^ 1) * 4096);
                gld16(Whh + goW2 + k0 + 32, ldW2 + (bf ^ 1) * 4096);
            }
            const int kb = lane >> 4;
            short8 Av[2], Wv[4];
#pragma unroll
            for (int i = 0; i < 2; ++i)
                Av[i] = *(const short8*)&sA[bf][kb][wr * 32 + i * 16 + rr][0];
#pragma unroll
            for (int g = 0; g < 4; ++g)
                Wv[g] = *(const short8*)&sW[bf][kb][wc * 64 + g * 16 + rr][0];
#pragma unroll
            for (int i = 0; i < 2; ++i)
#pragma unroll
                for (int g = 0; g < 4; ++g)
                    acc[i][g] = __builtin_amdgcn_mfma_f32_16x16x32_bf16(Av[i], Wv[g], acc[i][g], 0, 0, 0);
            __syncthreads();
        }
    }

    float* __restrict__ cb = cbAll + (size_t)l * SH;
    float* __restrict__ hf = hfinAll + (size_t)l * SH;
    u16* __restrict__ ho = houtAll + (size_t)l * SH;
#pragma unroll
    for (int i = 0; i < 2; ++i) {
#pragma unroll
        for (int q = 0; q < 4; ++q) {
            const int b = m0 + wr * 32 + i * 16 + rg * 4 + q;
            const float pi = acc[i][0][q] + bf2f(gr[i][0][q]);
            const float pf = acc[i][1][q] + bf2f(gr[i][1][q]);
            const float pg = acc[i][2][q] + bf2f(gr[i][2][q]);
            const float po = acc[i][3][q] + bf2f(gr[i][3][q]);
            const size_t idx = (size_t)b * HID + j;
            const float cprev = do_gemm ? cb[idx] : 0.f;
            const float cn = sigf(pf) * cprev + sigf(pi) * tanhf(pg);
            cb[idx] = cn;
            const float h = sigf(po) * tanhf(cn);
            if (write_hfin) hf[idx] = h;
            else            ho[idx] = f2bf(h);
        }
    }
}

// fused[b, n] = prod over streams of concat(h_fwd, h_rev); hfin layout [l][b][j]
__global__ void fuse_mul_kernel(const float* __restrict__ hfin, float* __restrict__ fused)
{
    const int idx = blockIdx.x * blockDim.x + threadIdx.x;
    if (idx >= BATCH * 2 * HID) return;
    const int b = idx >> 11;
    const int n = idx & 2047;
    const int half = n >> 10;
    const int j = n & 1023;
    const size_t o = (size_t)b * HID + j;
    fused[idx] = hfin[(size_t)(0 + half) * SH + o] *
                 hfin[(size_t)(2 + half) * SH + o] *
                 hfin[(size_t)(4 + half) * SH + o];
}

// fp32 vector GEMM for the small classifier (N=200): C = A@W^T + b
__launch_bounds__(256)
__global__ void gemm_bias_kernel(const float* __restrict__ A, const float* __restrict__ W,
                                 const float* __restrict__ b1,
                                 float* __restrict__ C, int M, int N, int K)
{
    __shared__ float As[16][68];
    __shared__ float Ws[16][68];
    const int tid = threadIdx.x;
    const int tx = tid & 15, ty = tid >> 4;
    const int m0 = blockIdx.x * 64;
    const int n0 = blockIdx.y * 64;
    const int lr = tid >> 2;
    const int lk = (tid & 3) << 2;
    const bool mok = (m0 + lr < M);
    const bool nok = (n0 + lr < N);
    const float* Arow = A + (size_t)(m0 + lr) * K + lk;
    const float* Wrow = W + (size_t)(n0 + lr) * K + lk;
    float acc[4][4] = {};

    for (int k0 = 0; k0 < K; k0 += 16) {
        float4 av = make_float4(0.f, 0.f, 0.f, 0.f);
        float4 wv = make_float4(0.f, 0.f, 0.f, 0.f);
        if (mok) av = *(const float4*)(Arow + k0);
        if (nok) wv = *(const float4*)(Wrow + k0);
        As[lk + 0][lr] = av.x; As[lk + 1][lr] = av.y; As[lk + 2][lr] = av.z; As[lk + 3][lr] = av.w;
        Ws[lk + 0][lr] = wv.x; Ws[lk + 1][lr] = wv.y; Ws[lk + 2][lr] = wv.z; Ws[lk + 3][lr] = wv.w;
        __syncthreads();
#pragma unroll
        for (int k = 0; k < 16; ++k) {
            const float4 a = *(const float4*)&As[k][ty << 2];
            const float4 ww = *(const float4*)&Ws[k][tx << 2];
            const float a4[4] = {a.x, a.y, a.z, a.w};
            const float w4[4] = {ww.x, ww.y, ww.z, ww.w};
#pragma unroll
            for (int i = 0; i < 4; ++i)
#pragma unroll
                for (int j = 0; j < 4; ++j)
                    acc[i][j] = fmaf(a4[i], w4[j], acc[i][j]);
        }
        __syncthreads();
    }

#pragma unroll
    for (int i = 0; i < 4; ++i) {
        const int m = m0 + (ty << 2) + i;
        if (m >= M) continue;
#pragma unroll
        for (int j = 0; j < 4; ++j) {
            const int n = n0 + (tx << 2) + j;
            if (n >= N) continue;
            C[(size_t)m * N + n] = acc[i][j] + (b1 ? b1[n] : 0.f);
        }
    }
}

extern "C" void kernel_launch(void* const* d_in, const int* in_sizes, int n_in,
                              void* d_out, int out_size, void* d_ws, size_t ws_size,
                              hipStream_t stream)
{
    const float* resnet   = (const float*)d_in[0];
    const float* c3d      = (const float*)d_in[1];
    const float* audio    = (const float*)d_in[2];
    const float* W_audio  = (const float*)d_in[3];
    const float* b_audio  = (const float*)d_in[4];
    const float* W_resnet = (const float*)d_in[5];
    const float* b_resnet = (const float*)d_in[6];
    const float* W_c3d    = (const float*)d_in[7];
    const float* b_c3d    = (const float*)d_in[8];
    const float* Wih[6]; const float* Whh[6]; const float* bih[6]; const float* bhh[6];
    for (int l = 0; l < 6; ++l) {
        Wih[l] = (const float*)d_in[9 + 4 * l];
        Whh[l] = (const float*)d_in[10 + 4 * l];
        bih[l] = (const float*)d_in[11 + 4 * l];
        bhh[l] = (const float*)d_in[12 + 4 * l];
    }
    const float* W_out = (const float*)d_in[33];
    const float* b_out = (const float*)d_in[34];
    float* out = (float*)d_out;

    const float* feat[3] = { audio, resnet, c3d };
    const float* fw[3]   = { W_audio, W_resnet, W_c3d };
    const float* fb[3]   = { b_audio, b_resnet, b_c3d };
    const int    fK[3]   = { 128, 2048, 4096 };

    // ---- workspace carve (bytes); featB aliased into G[2] (written last) ----
    char* p = (char*)d_ws;
    char* pend = p + ws_size;
    auto alloc = [&](size_t bytes) -> void* {
        void* q = p; p += (bytes + 255) & ~(size_t)255; return q;
    };
    const size_t FW = (size_t)1024 * (128 + 2048 + 4096);
    u16* Gall  = (u16*)alloc((size_t)3 * BT * NG * 2);       // 503 MB, bf16 pack4 t-major
    u16* featB = Gall + (size_t)2 * BT * NG;                 // alias: inside G[2]
    u16* fwB   = (u16*)alloc(FW * 2);
    u16* wihB  = (u16*)alloc((size_t)NG * HID * 2);          // reused per stream
    u16* whhB  = (u16*)alloc((size_t)3 * NG * HID * 2);      // all 6, [l][4096][1024]
    u16* projB = (u16*)alloc((size_t)BT * HID * 2);          // t-major rows
    float* bcat = (float*)alloc((size_t)NG * 4);
    u16* hA    = (u16*)alloc((size_t)6 * SH * 2);
    u16* hB    = (u16*)alloc((size_t)6 * SH * 2);
    float* cb    = (float*)alloc((size_t)6 * SH * 4);
    float* hfin  = (float*)alloc((size_t)6 * SH * 4);
    float* fused = (float*)alloc((size_t)BATCH * 2 * HID * 4);
    // audio fast-path buffers
    u16* waT      = (u16*)alloc((size_t)128 * 1024 * 2);     // W_audio^T bf16
    u16* wcombB   = (u16*)alloc((size_t)NG * 128 * 2);       // Wih_audio @ W_audio, bf16
    u16* featPerm = (u16*)alloc((size_t)BT * 128 * 2);       // audio feats t-major bf16
    float* bvec   = (float*)alloc((size_t)NG * 4);
    if (p > pend) {
        fprintf(stderr, "kernel_launch: ws too small: need %zu have %zu\n",
                (size_t)(p - (char*)d_ws), ws_size);
        return;
    }

    const dim3 blk(256);
    const size_t fwOff[3] = { 0, (size_t)1024 * 128, (size_t)1024 * 128 + (size_t)1024 * 2048 };
    const int n4w = (G4 * HID) / 4;

    // cvt resnet/c3d projection weights to bf16 (audio uses the fused path)
    for (int st = 1; st < 3; ++st) {
        const int n4 = (1024 * fK[st]) / 4;
        cvt4_kernel<<<dim3(min(2048, (n4 + 255) / 256)), blk, 0, stream>>>(
            fw[st], fwB + fwOff[st], n4);
    }
    // all 6 Whh in one batched launch
    {
        CvtBatch b6;
        for (int l = 0; l < 6; ++l) { b6.j[l].src = Whh[l]; b6.j[l].dst = whhB + (size_t)l * G4 * HID; }
        cvt4_batch<<<dim3(768, 6), blk, 0, stream>>>(b6, n4w);
    }

    // ---- stream 0 (audio), fused: G_a = feat_a @ (Wih_a W_a)^T + (Wih_a b_a + bcat) ----
    {
        CvtBatch b2;
        for (int d = 0; d < 2; ++d) { b2.j[d].src = Wih[d]; b2.j[d].dst = wihB + (size_t)d * G4 * HID; }
        cvt4_batch<<<dim3(768, 2), blk, 0, stream>>>(b2, n4w);
        transpose_cvt<<<dim3(512), blk, 0, stream>>>(W_audio, waT);
        // Wcomb (8192 x 128) = wihB (8192x1024) @ waT^T
        gemm_b16<2><<<dim3(64), blk, 0, stream>>>(wihB, waT, nullptr, wcombB, NG, 128, 1024, 8);
        bvec_kernel<<<dim3(2048), blk, 0, stream>>>(
            Wih[0], Wih[1], b_audio, bih[0], bhh[0], bih[1], bhh[1], bvec);
        cvtperm_audio<<<dim3((BT * 128 / 4 + 255) / 256), blk, 0, stream>>>(audio, featPerm);
        // G_audio (pack4 t-major) = featPerm (BTx128) @ wcombB^T + bvec, K=128
        gemm_b16<1><<<dim3((BT / 128) * (NG / 128)), blk, 0, stream>>>(
            featPerm, wcombB, bvec, Gall, BT, NG, 128, 8);
    }

    // ---- streams 1,2: feat cvt -> proj (t-major) -> Wih cvt -> G-GEMM ----
    for (int st = 1; st < 3; ++st) {
        const int K = fK[st];
        cvt4_kernel<<<dim3(2048), blk, 0, stream>>>(feat[st], featB, (BT * K) / 4);
        gemm_b16<0><<<dim3((BT / 128) * (HID / 128)), blk, 0, stream>>>(
            featB, fwB + fwOff[st], fb[st], projB, BT, HID, K, 8);
        {
            CvtBatch b2;
            for (int d = 0; d < 2; ++d) {
                b2.j[d].src = Wih[st * 2 + d];
                b2.j[d].dst = wihB + (size_t)d * G4 * HID;
            }
            cvt4_batch<<<dim3(768, 2), blk, 0, stream>>>(b2, n4w);
        }
        bias_cat_kernel<<<dim3(NG / 256), blk, 0, stream>>>(
            bih[st * 2], bhh[st * 2], bih[st * 2 + 1], bhh[st * 2 + 1], bcat);
        // writes G[st]; for st==2 this overwrites featB (dead after proj above)
        gemm_b16<1><<<dim3((BT / 128) * (NG / 128)), blk, 0, stream>>>(
            projB, wihB, bcat, Gall + (size_t)st * BT * NG, BT, NG, HID, 8);
    }

    // ---- merged recurrence: 20 launches, all 6 LSTMs per launch ----
    for (int s = 0; s < TT; ++s) {
        const u16* in = (s & 1) ? hB : hA;
        u16*      o  = (s & 1) ? hA : hB;
        lstm_step6<<<dim3(HID / 32, BATCH / 64, 6), blk, 0, stream>>>(
            whhB, Gall, in, o, cb, hfin, s, s == TT - 1 ? 1 : 0);
    }

    // fused elementwise product
    fuse_mul_kernel<<<dim3((BATCH * 2 * HID) / 256), blk, 0, stream>>>(hfin, fused);

    // classifier
    gemm_bias_kernel<<<dim3(BATCH / 64, (NCLS + 63) / 64), blk, 0, stream>>>(
        fused, W_out, b_out, out, BATCH, NCLS, 2 * HID);
}